// Round 1
// baseline (651.889 us; speedup 1.0000x reference)
//
#include <hip/hip_runtime.h>

// TriangleMultiplicationCpp (OUTGOING), N=512, C=128, fp32 in/out.
// Round 2: MFMA for k1 (projections) and k2 (triangle contraction).
// Workspace layout (bytes), all 67,108,864 each:
//   aT[c][m] @ 0        bT[c][m] @ 64M      g[m][d] @ 128M      tT[c][m] @ 192M
// where m = row*512 + col (position index), c = channel plane.

#define NN 512
#define CC 128
#define NPOS (NN * NN)
#define LN_EPS 1e-5f

typedef __attribute__((ext_vector_type(8))) short bf16x8;
typedef __attribute__((ext_vector_type(4))) float f32x4;

__device__ __forceinline__ float bitf(unsigned int u) {
    return __builtin_bit_cast(float, u);
}
__device__ __forceinline__ float b2f(unsigned short u) {
    return bitf(((unsigned int)u) << 16);
}
__device__ __forceinline__ unsigned short f2b(float f) {
    unsigned int u = __builtin_bit_cast(unsigned int, f);
    u = u + 0x7FFFu + ((u >> 16) & 1u);   // RTNE
    return (unsigned short)(u >> 16);
}
__device__ __forceinline__ float sigmoidf(float x) {
    return 1.0f / (1.0f + __expf(-x));
}

// ---------------------------------------------------------------------------
// Kernel 1: LN(act) -> proj/gate/glin via MFMA bf16.
// Block: 256 threads (4 waves), 128 positions. 10 chunks of 64 W-rows:
//   chunks 0..7: interleaved (proj,gate) pairs, d = chunk*32 + r/2
//   chunks 8..9: W_glin rows.
// Wave tile: 64m x 32n (4 M-frags x 2 N-frags x 4 K-steps of 16x16x32).
// Epilogue: frag dump -> LDS (aliasing W buffer) -> gated, transposed writes:
//   a/b planes get [D][m] rows (128B-coalesced), g stays [m][d].
// ---------------------------------------------------------------------------
__global__ __launch_bounds__(256) void k_ln_proj(
    const float* __restrict__ act, const float* __restrict__ mask,
    const float* __restrict__ lw, const float* __restrict__ lb,
    const float* __restrict__ Wproj, const float* __restrict__ Wgate,
    const float* __restrict__ Wglin,
    unsigned short* __restrict__ a_ws, unsigned short* __restrict__ b_ws,
    unsigned short* __restrict__ g_ws)
{
    __shared__ __align__(16) unsigned short Xs[128 * 136];  // 34816 B, bf16 X
    __shared__ __align__(16) float WL[4352];                // 17408 B union:
    unsigned short* Wu = (unsigned short*)WL;               //  bf16 W 64x136 / f32 Lacc 64x66

    const int tid = threadIdx.x;
    const int m0 = blockIdx.x * 128;

    // --- Phase 1: coalesced act load + LN + bf16 write to Xs ---
    {
        const int c4 = tid & 31;                  // float4 index within row
        float4 w4 = *(const float4*)(lw + c4 * 4);
        float4 b4 = *(const float4*)(lb + c4 * 4);
        for (int it = 0; it < 16; ++it) {
            int p = (tid >> 5) + it * 8;          // row 0..127
            float4 v = *(const float4*)(act + (size_t)(m0 + p) * CC + c4 * 4);
            float s  = v.x + v.y + v.z + v.w;
            float ss = v.x * v.x + v.y * v.y + v.z * v.z + v.w * v.w;
            #pragma unroll
            for (int ofs = 1; ofs < 32; ofs <<= 1) {
                s  += __shfl_xor(s, ofs);
                ss += __shfl_xor(ss, ofs);
            }
            float mean = s * (1.0f / 128.0f);
            float var  = ss * (1.0f / 128.0f) - mean * mean;
            float rstd = rsqrtf(var + LN_EPS);
            ushort4 o;
            o.x = f2b((v.x - mean) * rstd * w4.x + b4.x);
            o.y = f2b((v.y - mean) * rstd * w4.y + b4.y);
            o.z = f2b((v.z - mean) * rstd * w4.z + b4.z);
            o.w = f2b((v.w - mean) * rstd * w4.w + b4.w);
            *(ushort4*)&Xs[p * 136 + c4 * 4] = o;
        }
    }

    const int lane  = tid & 63;
    const int wid   = tid >> 6;
    const int row16 = lane & 15, kg = lane >> 4;
    const int wrm = (wid >> 1) * 64;   // wave m-base
    const int wcn = (wid & 1) * 32;    // wave n-base

    for (int chunk = 0; chunk < 10; ++chunk) {
        __syncthreads();
        // --- stage 64 W rows (fp32 -> bf16) ---
        {
            int r = tid >> 2, q = tid & 3;
            const float* wrow;
            if (chunk < 8) {
                int d = chunk * 32 + (r >> 1);
                wrow = (r & 1) ? (Wgate + d * CC) : (Wproj + d * CC);
            } else {
                wrow = Wglin + ((chunk - 8) * 64 + r) * CC;
            }
            #pragma unroll
            for (int t = 0; t < 8; ++t) {
                float4 v = *(const float4*)(wrow + q * 32 + t * 4);
                ushort4 o;
                o.x = f2b(v.x); o.y = f2b(v.y); o.z = f2b(v.z); o.w = f2b(v.w);
                *(ushort4*)&Wu[r * 136 + q * 32 + t * 4] = o;
            }
        }
        __syncthreads();

        // --- MFMA: 4 Mf x 2 Nf x 4 Ks ---
        f32x4 acc[4][2] = {};
        #pragma unroll
        for (int ks = 0; ks < 4; ++ks) {
            const int koff = ks * 32 + kg * 8;
            bf16x8 xa[4], wb[2];
            #pragma unroll
            for (int mf = 0; mf < 4; ++mf)
                xa[mf] = *(const bf16x8*)&Xs[(wrm + mf * 16 + row16) * 136 + koff];
            #pragma unroll
            for (int nf = 0; nf < 2; ++nf)
                wb[nf] = *(const bf16x8*)&Wu[(wcn + nf * 16 + row16) * 136 + koff];
            #pragma unroll
            for (int mf = 0; mf < 4; ++mf)
                #pragma unroll
                for (int nf = 0; nf < 2; ++nf)
                    acc[mf][nf] = __builtin_amdgcn_mfma_f32_16x16x32_bf16(
                        xa[mf], wb[nf], acc[mf][nf], 0, 0, 0);
        }

        // --- epilogue, two m-halves through the Lacc union buffer ---
        for (int h = 0; h < 2; ++h) {
            __syncthreads();
            if ((wid >> 1) == h) {
                #pragma unroll
                for (int nf = 0; nf < 2; ++nf) {
                    #pragma unroll
                    for (int mf = 0; mf < 4; ++mf) {
                        int r = wcn + nf * 16 + row16;       // logit row 0..63
                        int mloc = mf * 16 + kg * 4;         // m within half
                        float* dst = &WL[r * 66 + mloc];
                        f32x4 v = acc[mf][nf];
                        *(float2*)(dst)     = make_float2(v.x, v.y);
                        *(float2*)(dst + 2) = make_float2(v.z, v.w);
                    }
                }
            }
            __syncthreads();
            if (chunk < 8) {
                int dd = tid >> 3, mseg = tid & 7;   // 32 d x 8 m-segments
                float4 p0 = *(const float4*)&WL[(2 * dd) * 66 + mseg * 8];
                float4 p1 = *(const float4*)&WL[(2 * dd) * 66 + mseg * 8 + 4];
                float4 g0 = *(const float4*)&WL[(2 * dd + 1) * 66 + mseg * 8];
                float4 g1 = *(const float4*)&WL[(2 * dd + 1) * 66 + mseg * 8 + 4];
                const float* mkp = mask + m0 + h * 64 + mseg * 8;
                float4 mk0 = *(const float4*)(mkp);
                float4 mk1 = *(const float4*)(mkp + 4);
                unsigned short ob[8];
                ob[0] = f2b(p0.x * mk0.x * sigmoidf(g0.x));
                ob[1] = f2b(p0.y * mk0.y * sigmoidf(g0.y));
                ob[2] = f2b(p0.z * mk0.z * sigmoidf(g0.z));
                ob[3] = f2b(p0.w * mk0.w * sigmoidf(g0.w));
                ob[4] = f2b(p1.x * mk1.x * sigmoidf(g1.x));
                ob[5] = f2b(p1.y * mk1.y * sigmoidf(g1.y));
                ob[6] = f2b(p1.z * mk1.z * sigmoidf(g1.z));
                ob[7] = f2b(p1.w * mk1.w * sigmoidf(g1.w));
                unsigned short* plane = (chunk < 4) ? a_ws : b_ws;
                int D = (chunk & 3) * 32 + dd;
                uint4 w;
                w.x = (unsigned)ob[0] | ((unsigned)ob[1] << 16);
                w.y = (unsigned)ob[2] | ((unsigned)ob[3] << 16);
                w.z = (unsigned)ob[4] | ((unsigned)ob[5] << 16);
                w.w = (unsigned)ob[6] | ((unsigned)ob[7] << 16);
                *(uint4*)(plane + (size_t)D * NPOS + m0 + h * 64 + mseg * 8) = w;
            } else {
                int mm = tid >> 2, q = tid & 3;      // 64 m x 4 r-groups of 16
                unsigned short ob[16];
                #pragma unroll
                for (int rr = 0; rr < 16; ++rr)
                    ob[rr] = f2b(sigmoidf(WL[(q * 16 + rr) * 66 + mm]));
                uint4 w0, w1;
                w0.x = (unsigned)ob[0]  | ((unsigned)ob[1]  << 16);
                w0.y = (unsigned)ob[2]  | ((unsigned)ob[3]  << 16);
                w0.z = (unsigned)ob[4]  | ((unsigned)ob[5]  << 16);
                w0.w = (unsigned)ob[6]  | ((unsigned)ob[7]  << 16);
                w1.x = (unsigned)ob[8]  | ((unsigned)ob[9]  << 16);
                w1.y = (unsigned)ob[10] | ((unsigned)ob[11] << 16);
                w1.z = (unsigned)ob[12] | ((unsigned)ob[13] << 16);
                w1.w = (unsigned)ob[14] | ((unsigned)ob[15] << 16);
                unsigned short* gp = g_ws + (size_t)(m0 + h * 64 + mm) * CC +
                                     (chunk - 8) * 64 + q * 16;
                *(uint4*)gp = w0;
                *(uint4*)(gp + 8) = w1;
            }
        }
    }
}

// ---------------------------------------------------------------------------
// Kernel 2: per-channel GEMM  tT[c] = A_c * B_c^T  (A=aT[c], B=bT[c], 512x512).
// Block: 128x128 tile, 256 threads (4 waves, 64x64 each), BK=64, K=512.
// Staging: global_load_lds width-16 into linear LDS with pre-swizzled global
// source; frag ds_read applies the same XOR (byte ^= (row&7)<<4) -> each
// bank-quad hit exactly 8x per wave read (conflict-uniform).
// ---------------------------------------------------------------------------
__global__ __launch_bounds__(256) void k_tri(
    const unsigned short* __restrict__ a_ws,
    const unsigned short* __restrict__ b_ws,
    unsigned short* __restrict__ t_ws)
{
    __shared__ __align__(16) unsigned short As[8192];   // 128 x 64 bf16 (swizzled)
    __shared__ __align__(16) unsigned short Bs[8192];

    const int tid  = threadIdx.x;
    const int lane = tid & 63;
    const int wid  = tid >> 6;
    const int c    = blockIdx.y;
    const int i0   = (blockIdx.x >> 2) * 128;
    const int j0   = (blockIdx.x & 3) * 128;

    const size_t plane = (size_t)c * NPOS;
    const unsigned short* Ag = a_ws + plane + (size_t)i0 * NN;
    const unsigned short* Bg = b_ws + plane + (size_t)j0 * NN;

    const int row16 = lane & 15, kg = lane >> 4;
    const int wrm = (wid >> 1) * 64;
    const int wcn = (wid & 1) * 64;
    const int xr  = (lane & 7) << 4;    // frag-read XOR (bytes)

    // staging source offsets (elements): inverse-swizzle the linear LDS slot
    int srcOff[4];
    #pragma unroll
    for (int q = 0; q < 4; ++q) {
        int p  = (wid * 4 + q) * 1024 + lane * 16;       // physical LDS byte
        int lg = p ^ (((p >> 7) & 7) << 4);              // logical byte
        int r = lg >> 7, k16 = (lg >> 4) & 7;
        srcOff[q] = r * NN + k16 * 8;
    }

    f32x4 acc[4][4] = {};

    for (int kt = 0; kt < 8; ++kt) {
        const int k0 = kt * 64;
        __syncthreads();
        #pragma unroll
        for (int q = 0; q < 4; ++q) {
            int ldsOff = (wid * 4 + q) * 512;   // ushort units = 1024 B chunks
            __builtin_amdgcn_global_load_lds(
                (const __attribute__((address_space(1))) void*)(Ag + srcOff[q] + k0),
                (__attribute__((address_space(3))) void*)(As + ldsOff), 16, 0, 0);
            __builtin_amdgcn_global_load_lds(
                (const __attribute__((address_space(1))) void*)(Bg + srcOff[q] + k0),
                (__attribute__((address_space(3))) void*)(Bs + ldsOff), 16, 0, 0);
        }
        __syncthreads();

        #pragma unroll
        for (int ks = 0; ks < 2; ++ks) {
            const int kb = ks * 64 + kg * 16;   // byte offset within 128B row
            bf16x8 af[4], bfr[4];
            #pragma unroll
            for (int mf = 0; mf < 4; ++mf) {
                int lA = ((wrm + mf * 16 + row16) << 7) + kb;
                af[mf] = *(const bf16x8*)((const char*)As + (lA ^ xr));
            }
            #pragma unroll
            for (int nf = 0; nf < 4; ++nf) {
                int lB = ((wcn + nf * 16 + row16) << 7) + kb;
                bfr[nf] = *(const bf16x8*)((const char*)Bs + (lB ^ xr));
            }
            #pragma unroll
            for (int mf = 0; mf < 4; ++mf)
                #pragma unroll
                for (int nf = 0; nf < 4; ++nf)
                    acc[mf][nf] = __builtin_amdgcn_mfma_f32_16x16x32_bf16(
                        af[mf], bfr[nf], acc[mf][nf], 0, 0, 0);
        }
    }

    // write tT[c][i*512 + j] (bf16)
    unsigned short* tp = t_ws + plane;
    #pragma unroll
    for (int mf = 0; mf < 4; ++mf) {
        int i = i0 + wrm + mf * 16 + kg * 4;
        #pragma unroll
        for (int nf = 0; nf < 4; ++nf) {
            int j = j0 + wcn + nf * 16 + row16;
            f32x4 v = acc[mf][nf];
            tp[(size_t)(i + 0) * NN + j] = f2b(v.x);
            tp[(size_t)(i + 1) * NN + j] = f2b(v.y);
            tp[(size_t)(i + 2) * NN + j] = f2b(v.z);
            tp[(size_t)(i + 3) * NN + j] = f2b(v.w);
        }
    }
}

// ---------------------------------------------------------------------------
// Kernel 3: out = (LN_c(t) @ W_out^T) * g.  fp32 VALU GEMM (accuracy headroom).
// Staging reads the transposed tT[c][m] layout in 128B-coalesced runs.
// ---------------------------------------------------------------------------
__global__ __launch_bounds__(256) void k_ln_out(
    const unsigned short* __restrict__ t_ws,
    const unsigned short* __restrict__ g_ws,
    const float* __restrict__ lw, const float* __restrict__ lb,
    const float* __restrict__ Wout,
    float* __restrict__ out)
{
    __shared__ float X[64 * 132];
    __shared__ unsigned short W[64 * 132];

    const int tid = threadIdx.x;
    const int m0 = blockIdx.x * 64;

    // stage t tile from tT[c][m] (bf16 -> fp32), transposing into X[m][c]
    for (int it = 0; it < 8; ++it) {
        int c  = it * 16 + (tid >> 4);
        int mm = (tid & 15) * 4;
        ushort4 u = *(const ushort4*)(t_ws + (size_t)c * NPOS + m0 + mm);
        X[(mm + 0) * 132 + c] = b2f(u.x);
        X[(mm + 1) * 132 + c] = b2f(u.y);
        X[(mm + 2) * 132 + c] = b2f(u.z);
        X[(mm + 3) * 132 + c] = b2f(u.w);
    }
    __syncthreads();

    // layernorm over c
    {
        int p = tid >> 2, q = tid & 3;
        float s = 0.f, ss = 0.f;
        #pragma unroll
        for (int t = 0; t < 32; ++t) {
            float v = X[p * 132 + q * 32 + t];
            s += v; ss += v * v;
        }
        s += __shfl_xor(s, 1); ss += __shfl_xor(ss, 1);
        s += __shfl_xor(s, 2); ss += __shfl_xor(ss, 2);
        float mean = s * (1.0f / 128.0f);
        float var  = ss * (1.0f / 128.0f) - mean * mean;
        float rstd = rsqrtf(var + LN_EPS);
        #pragma unroll
        for (int t = 0; t < 32; ++t) {
            int c = q * 32 + t;
            float v = X[p * 132 + c];
            X[p * 132 + c] = (v - mean) * rstd * lw[c] + lb[c];
        }
    }

    const int tx = tid & 15, ty = tid >> 4;

    for (int chunk = 0; chunk < 2; ++chunk) {
        __syncthreads();
        for (int idx = tid; idx < 64 * 32; idx += 256) {
            int r = idx >> 5, k4 = idx & 31;
            const float* wrow = Wout + (chunk * 64 + r) * CC;
            float4 v = *(const float4*)(wrow + k4 * 4);
            unsigned short* dst = &W[r * 132 + k4 * 4];
            dst[0] = f2b(v.x); dst[1] = f2b(v.y);
            dst[2] = f2b(v.z); dst[3] = f2b(v.w);
        }
        __syncthreads();

        float acc[4][4] = {};
        for (int k = 0; k < 128; k += 4) {
            float4 xr[4];
            #pragma unroll
            for (int pp = 0; pp < 4; ++pp)
                xr[pp] = *(const float4*)&X[(ty * 4 + pp) * 132 + k];
            #pragma unroll
            for (int dd = 0; dd < 4; ++dd) {
                const unsigned short* wp = &W[(tx * 4 + dd) * 132 + k];
                float w0 = b2f(wp[0]), w1 = b2f(wp[1]);
                float w2 = b2f(wp[2]), w3 = b2f(wp[3]);
                #pragma unroll
                for (int pp = 0; pp < 4; ++pp)
                    acc[pp][dd] += xr[pp].x * w0 + xr[pp].y * w1 +
                                   xr[pp].z * w2 + xr[pp].w * w3;
            }
        }

        #pragma unroll
        for (int pp = 0; pp < 4; ++pp) {
            int m = m0 + ty * 4 + pp;
            int d0 = chunk * 64 + tx * 4;
            const unsigned short* gp = g_ws + (size_t)m * CC + d0;
            float4 o;
            o.x = acc[pp][0] * b2f(gp[0]);
            o.y = acc[pp][1] * b2f(gp[1]);
            o.z = acc[pp][2] * b2f(gp[2]);
            o.w = acc[pp][3] * b2f(gp[3]);
            *(float4*)(out + (size_t)m * CC + d0) = o;
        }
    }
}

// ---------------------------------------------------------------------------
extern "C" void kernel_launch(void* const* d_in, const int* in_sizes, int n_in,
                              void* d_out, int out_size, void* d_ws, size_t ws_size,
                              hipStream_t stream) {
    const float* act   = (const float*)d_in[0];
    const float* mask  = (const float*)d_in[1];
    const float* lnw   = (const float*)d_in[2];
    const float* lnb   = (const float*)d_in[3];
    const float* Wproj = (const float*)d_in[4];
    const float* Wgate = (const float*)d_in[5];
    const float* lncw  = (const float*)d_in[6];
    const float* lncb  = (const float*)d_in[7];
    const float* Wout  = (const float*)d_in[8];
    const float* Wglin = (const float*)d_in[9];
    float* out = (float*)d_out;

    char* ws = (char*)d_ws;
    unsigned short* a_ws = (unsigned short*)(ws);
    unsigned short* b_ws = (unsigned short*)(ws + 67108864);
    unsigned short* g_ws = (unsigned short*)(ws + 134217728);
    unsigned short* t_ws = (unsigned short*)(ws + 201326592);

    k_ln_proj<<<dim3(2048), dim3(256), 0, stream>>>(
        act, mask, lnw, lnb, Wproj, Wgate, Wglin, a_ws, b_ws, g_ws);

    k_tri<<<dim3(16, 128), dim3(256), 0, stream>>>(a_ws, b_ws, t_ws);

    k_ln_out<<<dim3(4096), dim3(256), 0, stream>>>(
        t_ws, g_ws, lncw, lncb, Wout, out);
}

// Round 3
// 607.265 us; speedup vs baseline: 1.0735x; 1.0735x over previous
//
#include <hip/hip_runtime.h>

// TriangleMultiplicationCpp (OUTGOING), N=512, C=128, fp32 in/out.
// Round 4: k1/k2 as in R2 (verified). k3 = conflict-free fp32 VALU GEMM
// reading tT[c][m] c-major directly (no transpose kernel).
// Workspace layout (bytes), all 67,108,864 each:
//   aT[c][m] @ 0      bT[c][m] @ 64M      g[m][d] @ 128M      tT[c][m] @ 192M

#define NN 512
#define CC 128
#define NPOS (NN * NN)
#define LN_EPS 1e-5f

typedef __attribute__((ext_vector_type(8))) short bf16x8;
typedef __attribute__((ext_vector_type(4))) float f32x4;

__device__ __forceinline__ float bitf(unsigned int u) {
    return __builtin_bit_cast(float, u);
}
__device__ __forceinline__ float b2f(unsigned short u) {
    return bitf(((unsigned int)u) << 16);
}
__device__ __forceinline__ unsigned short f2b(float f) {
    unsigned int u = __builtin_bit_cast(unsigned int, f);
    u = u + 0x7FFFu + ((u >> 16) & 1u);   // RTNE
    return (unsigned short)(u >> 16);
}
__device__ __forceinline__ float sigmoidf(float x) {
    return 1.0f / (1.0f + __expf(-x));
}
__device__ __forceinline__ void unpack8(uint4 u, float* dst) {
    dst[0] = bitf(u.x << 16); dst[1] = bitf(u.x & 0xFFFF0000u);
    dst[2] = bitf(u.y << 16); dst[3] = bitf(u.y & 0xFFFF0000u);
    dst[4] = bitf(u.z << 16); dst[5] = bitf(u.z & 0xFFFF0000u);
    dst[6] = bitf(u.w << 16); dst[7] = bitf(u.w & 0xFFFF0000u);
}

// ---------------------------------------------------------------------------
// Kernel 1: LN(act) -> proj/gate/glin via MFMA bf16.  (unchanged from R2)
// ---------------------------------------------------------------------------
__global__ __launch_bounds__(256) void k_ln_proj(
    const float* __restrict__ act, const float* __restrict__ mask,
    const float* __restrict__ lw, const float* __restrict__ lb,
    const float* __restrict__ Wproj, const float* __restrict__ Wgate,
    const float* __restrict__ Wglin,
    unsigned short* __restrict__ a_ws, unsigned short* __restrict__ b_ws,
    unsigned short* __restrict__ g_ws)
{
    __shared__ __align__(16) unsigned short Xs[128 * 136];  // 34816 B, bf16 X
    __shared__ __align__(16) float WL[4352];                // 17408 B union
    unsigned short* Wu = (unsigned short*)WL;

    const int tid = threadIdx.x;
    const int m0 = blockIdx.x * 128;

    // --- Phase 1: coalesced act load + LN + bf16 write to Xs ---
    {
        const int c4 = tid & 31;
        float4 w4 = *(const float4*)(lw + c4 * 4);
        float4 b4 = *(const float4*)(lb + c4 * 4);
        for (int it = 0; it < 16; ++it) {
            int p = (tid >> 5) + it * 8;
            float4 v = *(const float4*)(act + (size_t)(m0 + p) * CC + c4 * 4);
            float s  = v.x + v.y + v.z + v.w;
            float ss = v.x * v.x + v.y * v.y + v.z * v.z + v.w * v.w;
            #pragma unroll
            for (int ofs = 1; ofs < 32; ofs <<= 1) {
                s  += __shfl_xor(s, ofs);
                ss += __shfl_xor(ss, ofs);
            }
            float mean = s * (1.0f / 128.0f);
            float var  = ss * (1.0f / 128.0f) - mean * mean;
            float rstd = rsqrtf(var + LN_EPS);
            ushort4 o;
            o.x = f2b((v.x - mean) * rstd * w4.x + b4.x);
            o.y = f2b((v.y - mean) * rstd * w4.y + b4.y);
            o.z = f2b((v.z - mean) * rstd * w4.z + b4.z);
            o.w = f2b((v.w - mean) * rstd * w4.w + b4.w);
            *(ushort4*)&Xs[p * 136 + c4 * 4] = o;
        }
    }

    const int lane  = tid & 63;
    const int wid   = tid >> 6;
    const int row16 = lane & 15, kg = lane >> 4;
    const int wrm = (wid >> 1) * 64;
    const int wcn = (wid & 1) * 32;

    for (int chunk = 0; chunk < 10; ++chunk) {
        __syncthreads();
        {
            int r = tid >> 2, q = tid & 3;
            const float* wrow;
            if (chunk < 8) {
                int d = chunk * 32 + (r >> 1);
                wrow = (r & 1) ? (Wgate + d * CC) : (Wproj + d * CC);
            } else {
                wrow = Wglin + ((chunk - 8) * 64 + r) * CC;
            }
            #pragma unroll
            for (int t = 0; t < 8; ++t) {
                float4 v = *(const float4*)(wrow + q * 32 + t * 4);
                ushort4 o;
                o.x = f2b(v.x); o.y = f2b(v.y); o.z = f2b(v.z); o.w = f2b(v.w);
                *(ushort4*)&Wu[r * 136 + q * 32 + t * 4] = o;
            }
        }
        __syncthreads();

        f32x4 acc[4][2] = {};
        #pragma unroll
        for (int ks = 0; ks < 4; ++ks) {
            const int koff = ks * 32 + kg * 8;
            bf16x8 xa[4], wb[2];
            #pragma unroll
            for (int mf = 0; mf < 4; ++mf)
                xa[mf] = *(const bf16x8*)&Xs[(wrm + mf * 16 + row16) * 136 + koff];
            #pragma unroll
            for (int nf = 0; nf < 2; ++nf)
                wb[nf] = *(const bf16x8*)&Wu[(wcn + nf * 16 + row16) * 136 + koff];
            #pragma unroll
            for (int mf = 0; mf < 4; ++mf)
                #pragma unroll
                for (int nf = 0; nf < 2; ++nf)
                    acc[mf][nf] = __builtin_amdgcn_mfma_f32_16x16x32_bf16(
                        xa[mf], wb[nf], acc[mf][nf], 0, 0, 0);
        }

        for (int h = 0; h < 2; ++h) {
            __syncthreads();
            if ((wid >> 1) == h) {
                #pragma unroll
                for (int nf = 0; nf < 2; ++nf) {
                    #pragma unroll
                    for (int mf = 0; mf < 4; ++mf) {
                        int r = wcn + nf * 16 + row16;
                        int mloc = mf * 16 + kg * 4;
                        float* dst = &WL[r * 66 + mloc];
                        f32x4 v = acc[mf][nf];
                        *(float2*)(dst)     = make_float2(v.x, v.y);
                        *(float2*)(dst + 2) = make_float2(v.z, v.w);
                    }
                }
            }
            __syncthreads();
            if (chunk < 8) {
                int dd = tid >> 3, mseg = tid & 7;
                float4 p0 = *(const float4*)&WL[(2 * dd) * 66 + mseg * 8];
                float4 p1 = *(const float4*)&WL[(2 * dd) * 66 + mseg * 8 + 4];
                float4 g0 = *(const float4*)&WL[(2 * dd + 1) * 66 + mseg * 8];
                float4 g1 = *(const float4*)&WL[(2 * dd + 1) * 66 + mseg * 8 + 4];
                const float* mkp = mask + m0 + h * 64 + mseg * 8;
                float4 mk0 = *(const float4*)(mkp);
                float4 mk1 = *(const float4*)(mkp + 4);
                unsigned short ob[8];
                ob[0] = f2b(p0.x * mk0.x * sigmoidf(g0.x));
                ob[1] = f2b(p0.y * mk0.y * sigmoidf(g0.y));
                ob[2] = f2b(p0.z * mk0.z * sigmoidf(g0.z));
                ob[3] = f2b(p0.w * mk0.w * sigmoidf(g0.w));
                ob[4] = f2b(p1.x * mk1.x * sigmoidf(g1.x));
                ob[5] = f2b(p1.y * mk1.y * sigmoidf(g1.y));
                ob[6] = f2b(p1.z * mk1.z * sigmoidf(g1.z));
                ob[7] = f2b(p1.w * mk1.w * sigmoidf(g1.w));
                unsigned short* plane = (chunk < 4) ? a_ws : b_ws;
                int D = (chunk & 3) * 32 + dd;
                uint4 w;
                w.x = (unsigned)ob[0] | ((unsigned)ob[1] << 16);
                w.y = (unsigned)ob[2] | ((unsigned)ob[3] << 16);
                w.z = (unsigned)ob[4] | ((unsigned)ob[5] << 16);
                w.w = (unsigned)ob[6] | ((unsigned)ob[7] << 16);
                *(uint4*)(plane + (size_t)D * NPOS + m0 + h * 64 + mseg * 8) = w;
            } else {
                int mm = tid >> 2, q = tid & 3;
                unsigned short ob[16];
                #pragma unroll
                for (int rr = 0; rr < 16; ++rr)
                    ob[rr] = f2b(sigmoidf(WL[(q * 16 + rr) * 66 + mm]));
                uint4 w0, w1;
                w0.x = (unsigned)ob[0]  | ((unsigned)ob[1]  << 16);
                w0.y = (unsigned)ob[2]  | ((unsigned)ob[3]  << 16);
                w0.z = (unsigned)ob[4]  | ((unsigned)ob[5]  << 16);
                w0.w = (unsigned)ob[6]  | ((unsigned)ob[7]  << 16);
                w1.x = (unsigned)ob[8]  | ((unsigned)ob[9]  << 16);
                w1.y = (unsigned)ob[10] | ((unsigned)ob[11] << 16);
                w1.z = (unsigned)ob[12] | ((unsigned)ob[13] << 16);
                w1.w = (unsigned)ob[14] | ((unsigned)ob[15] << 16);
                unsigned short* gp = g_ws + (size_t)(m0 + h * 64 + mm) * CC +
                                     (chunk - 8) * 64 + q * 16;
                *(uint4*)gp = w0;
                *(uint4*)(gp + 8) = w1;
            }
        }
    }
}

// ---------------------------------------------------------------------------
// Kernel 2: per-channel GEMM  tT[c] = A_c * B_c^T.  (unchanged from R2)
// ---------------------------------------------------------------------------
__global__ __launch_bounds__(256) void k_tri(
    const unsigned short* __restrict__ a_ws,
    const unsigned short* __restrict__ b_ws,
    unsigned short* __restrict__ t_ws)
{
    __shared__ __align__(16) unsigned short As[8192];
    __shared__ __align__(16) unsigned short Bs[8192];

    const int tid  = threadIdx.x;
    const int lane = tid & 63;
    const int wid  = tid >> 6;
    const int c    = blockIdx.y;
    const int i0   = (blockIdx.x >> 2) * 128;
    const int j0   = (blockIdx.x & 3) * 128;

    const size_t plane = (size_t)c * NPOS;
    const unsigned short* Ag = a_ws + plane + (size_t)i0 * NN;
    const unsigned short* Bg = b_ws + plane + (size_t)j0 * NN;

    const int row16 = lane & 15, kg = lane >> 4;
    const int wrm = (wid >> 1) * 64;
    const int wcn = (wid & 1) * 64;
    const int xr  = (lane & 7) << 4;

    int srcOff[4];
    #pragma unroll
    for (int q = 0; q < 4; ++q) {
        int p  = (wid * 4 + q) * 1024 + lane * 16;
        int lg = p ^ (((p >> 7) & 7) << 4);
        int r = lg >> 7, k16 = (lg >> 4) & 7;
        srcOff[q] = r * NN + k16 * 8;
    }

    f32x4 acc[4][4] = {};

    for (int kt = 0; kt < 8; ++kt) {
        const int k0 = kt * 64;
        __syncthreads();
        #pragma unroll
        for (int q = 0; q < 4; ++q) {
            int ldsOff = (wid * 4 + q) * 512;
            __builtin_amdgcn_global_load_lds(
                (const __attribute__((address_space(1))) void*)(Ag + srcOff[q] + k0),
                (__attribute__((address_space(3))) void*)(As + ldsOff), 16, 0, 0);
            __builtin_amdgcn_global_load_lds(
                (const __attribute__((address_space(1))) void*)(Bg + srcOff[q] + k0),
                (__attribute__((address_space(3))) void*)(Bs + ldsOff), 16, 0, 0);
        }
        __syncthreads();

        #pragma unroll
        for (int ks = 0; ks < 2; ++ks) {
            const int kb = ks * 64 + kg * 16;
            bf16x8 af[4], bfr[4];
            #pragma unroll
            for (int mf = 0; mf < 4; ++mf) {
                int lA = ((wrm + mf * 16 + row16) << 7) + kb;
                af[mf] = *(const bf16x8*)((const char*)As + (lA ^ xr));
            }
            #pragma unroll
            for (int nf = 0; nf < 4; ++nf) {
                int lB = ((wcn + nf * 16 + row16) << 7) + kb;
                bfr[nf] = *(const bf16x8*)((const char*)Bs + (lB ^ xr));
            }
            #pragma unroll
            for (int mf = 0; mf < 4; ++mf)
                #pragma unroll
                for (int nf = 0; nf < 4; ++nf)
                    acc[mf][nf] = __builtin_amdgcn_mfma_f32_16x16x32_bf16(
                        af[mf], bfr[nf], acc[mf][nf], 0, 0, 0);
        }
    }

    unsigned short* tp = t_ws + plane;
    #pragma unroll
    for (int mf = 0; mf < 4; ++mf) {
        int i = i0 + wrm + mf * 16 + kg * 4;
        #pragma unroll
        for (int nf = 0; nf < 4; ++nf) {
            int j = j0 + wcn + nf * 16 + row16;
            f32x4 v = acc[mf][nf];
            tp[(size_t)(i + 0) * NN + j] = f2b(v.x);
            tp[(size_t)(i + 1) * NN + j] = f2b(v.y);
            tp[(size_t)(i + 2) * NN + j] = f2b(v.z);
            tp[(size_t)(i + 3) * NN + j] = f2b(v.w);
        }
    }
}

// ---------------------------------------------------------------------------
// Kernel 3: out = (LN_c(t) @ W_out^T) * g.  fp32-X VALU GEMM (R2 numerics),
// conflict-free layouts:
//   Xf[c][m] fp32, stride 68  (c-major: staged straight from tT[c][m];
//                              GEMM reads are wave-broadcast float4)
//   Wt[c][d] bf16, stride 132 (transposed W: lane-varying d -> 2-way max)
// Block: 64 positions, full d=128. Thread: 4 m x 8 d outer product.
// ---------------------------------------------------------------------------
__global__ __launch_bounds__(256) void k_out(
    const unsigned short* __restrict__ tT,
    const unsigned short* __restrict__ g_ws,
    const float* __restrict__ lw, const float* __restrict__ lb,
    const float* __restrict__ Wout,
    float* __restrict__ out)
{
    __shared__ __align__(16) float Xf[128 * 68];            // 34816 B
    __shared__ __align__(16) unsigned short Wt[128 * 132];  // 33792 B

    const int tid = threadIdx.x;
    const int m0 = blockIdx.x * 64;

    // --- Phase 0: stage raw t (bf16 -> fp32), c-major. 128B runs per c-row.
    #pragma unroll
    for (int it = 0; it < 4; ++it) {
        int c  = (tid >> 3) + it * 32;
        int mg = tid & 7;
        uint4 u = *(const uint4*)(tT + (size_t)c * NPOS + m0 + mg * 8);
        float f[8];
        unpack8(u, f);
        float* dst = &Xf[c * 68 + mg * 8];
        #pragma unroll
        for (int t = 0; t < 8; ++t) dst[t] = f[t];
    }
    // --- Phase 0b: stage Wt[c][d] = bf16(Wout[d][c]) (transpose in LDS) ---
    #pragma unroll
    for (int it = 0; it < 16; ++it) {
        int idx = tid + it * 256;
        int d = idx >> 5, c4 = idx & 31;
        float4 v = *(const float4*)(Wout + d * CC + c4 * 4);
        Wt[(c4 * 4 + 0) * 132 + d] = f2b(v.x);
        Wt[(c4 * 4 + 1) * 132 + d] = f2b(v.y);
        Wt[(c4 * 4 + 2) * 132 + d] = f2b(v.z);
        Wt[(c4 * 4 + 3) * 132 + d] = f2b(v.w);
    }
    __syncthreads();

    // --- Phase 1: in-place LN over c, 4 lanes per m (quad shuffle) ---
    {
        int m = tid >> 2, q = tid & 3;
        float s = 0.f, ss = 0.f;
        #pragma unroll
        for (int t = 0; t < 32; ++t) {
            float v = Xf[(q * 32 + t) * 68 + m];
            s += v; ss += v * v;
        }
        s += __shfl_xor(s, 1); ss += __shfl_xor(ss, 1);
        s += __shfl_xor(s, 2); ss += __shfl_xor(ss, 2);
        float mean = s * (1.0f / 128.0f);
        float var  = ss * (1.0f / 128.0f) - mean * mean;
        float rstd = rsqrtf(var + LN_EPS);
        #pragma unroll
        for (int t = 0; t < 32; ++t) {
            int c = q * 32 + t;
            float v = Xf[c * 68 + m];
            Xf[c * 68 + m] = (v - mean) * rstd * lw[c] + lb[c];
        }
    }
    __syncthreads();

    // --- GEMM: thread (ty, tx) owns m = ty*4..+3, d = tx*8..+7 ---
    const int tx = tid & 15, ty = tid >> 4;
    float acc[4][8] = {};
    #pragma unroll 4
    for (int c = 0; c < 128; ++c) {
        float4 xv = *(const float4*)&Xf[c * 68 + ty * 4];
        const unsigned short* wp = &Wt[c * 132 + tx * 8];
        uint2 wa = *(const uint2*)(wp);
        uint2 wbu = *(const uint2*)(wp + 4);
        float w[8];
        w[0] = bitf(wa.x << 16);  w[1] = bitf(wa.x & 0xFFFF0000u);
        w[2] = bitf(wa.y << 16);  w[3] = bitf(wa.y & 0xFFFF0000u);
        w[4] = bitf(wbu.x << 16); w[5] = bitf(wbu.x & 0xFFFF0000u);
        w[6] = bitf(wbu.y << 16); w[7] = bitf(wbu.y & 0xFFFF0000u);
        float xr[4] = {xv.x, xv.y, xv.z, xv.w};
        #pragma unroll
        for (int i2 = 0; i2 < 4; ++i2)
            #pragma unroll
            for (int j = 0; j < 8; ++j)
                acc[i2][j] += xr[i2] * w[j];
    }

    // --- epilogue: gate with g, float4 stores ---
    #pragma unroll
    for (int i2 = 0; i2 < 4; ++i2) {
        int m = m0 + ty * 4 + i2;
        const unsigned short* gp = g_ws + (size_t)m * CC + tx * 8;
        ushort4 ga = *(const ushort4*)(gp);
        ushort4 gb = *(const ushort4*)(gp + 4);
        float4 o0, o1;
        o0.x = acc[i2][0] * b2f(ga.x);
        o0.y = acc[i2][1] * b2f(ga.y);
        o0.z = acc[i2][2] * b2f(ga.z);
        o0.w = acc[i2][3] * b2f(ga.w);
        o1.x = acc[i2][4] * b2f(gb.x);
        o1.y = acc[i2][5] * b2f(gb.y);
        o1.z = acc[i2][6] * b2f(gb.z);
        o1.w = acc[i2][7] * b2f(gb.w);
        *(float4*)(out + (size_t)m * CC + tx * 8) = o0;
        *(float4*)(out + (size_t)m * CC + tx * 8 + 4) = o1;
    }
}

// ---------------------------------------------------------------------------
extern "C" void kernel_launch(void* const* d_in, const int* in_sizes, int n_in,
                              void* d_out, int out_size, void* d_ws, size_t ws_size,
                              hipStream_t stream) {
    const float* act   = (const float*)d_in[0];
    const float* mask  = (const float*)d_in[1];
    const float* lnw   = (const float*)d_in[2];
    const float* lnb   = (const float*)d_in[3];
    const float* Wproj = (const float*)d_in[4];
    const float* Wgate = (const float*)d_in[5];
    const float* lncw  = (const float*)d_in[6];
    const float* lncb  = (const float*)d_in[7];
    const float* Wout  = (const float*)d_in[8];
    const float* Wglin = (const float*)d_in[9];
    float* out = (float*)d_out;

    char* ws = (char*)d_ws;
    unsigned short* a_ws = (unsigned short*)(ws);
    unsigned short* b_ws = (unsigned short*)(ws + 67108864);
    unsigned short* g_ws = (unsigned short*)(ws + 134217728);
    unsigned short* t_ws = (unsigned short*)(ws + 201326592);

    k_ln_proj<<<dim3(2048), dim3(256), 0, stream>>>(
        act, mask, lnw, lnb, Wproj, Wgate, Wglin, a_ws, b_ws, g_ws);

    k_tri<<<dim3(16, 128), dim3(256), 0, stream>>>(a_ws, b_ws, t_ws);

    k_out<<<dim3(4096), dim3(256), 0, stream>>>(
        t_ws, g_ws, lncw, lncb, Wout, out);
}

// Round 4
// 566.181 us; speedup vs baseline: 1.1514x; 1.0726x over previous
//
#include <hip/hip_runtime.h>

// TriangleMultiplicationCpp (OUTGOING), N=512, C=128, fp32 in/out.
// Round 5: k1 uses pre-formatted bf16 weights (k_wprep) via global_load_lds
// + register-direct shfl-gated epilogue. k2 gets XCD-aware channel swizzle.
// Workspace layout (bytes), all 67,108,864 each:
//   aT[c][m] @ 0      bT[c][m] @ 64M      g[m][d] @ 128M      tT[c][m] @ 192M
// Wpb (160 KB bf16 weight image) overlays the head of the tT region:
// written by k_wprep, read by k1, then overwritten by k2. Stream-ordered.

#define NN 512
#define CC 128
#define NPOS (NN * NN)
#define LN_EPS 1e-5f

typedef __attribute__((ext_vector_type(8))) short bf16x8;
typedef __attribute__((ext_vector_type(4))) float f32x4;

__device__ __forceinline__ float bitf(unsigned int u) {
    return __builtin_bit_cast(float, u);
}
__device__ __forceinline__ float b2f(unsigned short u) {
    return bitf(((unsigned int)u) << 16);
}
__device__ __forceinline__ unsigned short f2b(float f) {
    unsigned int u = __builtin_bit_cast(unsigned int, f);
    u = u + 0x7FFFu + ((u >> 16) & 1u);   // RTNE
    return (unsigned short)(u >> 16);
}
__device__ __forceinline__ float sigmoidf(float x) {
    return 1.0f / (1.0f + __expf(-x));
}
__device__ __forceinline__ void unpack8(uint4 u, float* dst) {
    dst[0] = bitf(u.x << 16); dst[1] = bitf(u.x & 0xFFFF0000u);
    dst[2] = bitf(u.y << 16); dst[3] = bitf(u.y & 0xFFFF0000u);
    dst[4] = bitf(u.z << 16); dst[5] = bitf(u.z & 0xFFFF0000u);
    dst[6] = bitf(u.w << 16); dst[7] = bitf(u.w & 0xFFFF0000u);
}

// ---------------------------------------------------------------------------
// Kernel 0: weight prep. Builds the physical LDS image of each 64x128 bf16
// W chunk with the read-side XOR swizzle (byte p holds logical byte
// p ^ (((p>>8)&7)<<4)). 10 chunks x 16 KB.
// ---------------------------------------------------------------------------
__global__ __launch_bounds__(256) void k_wprep(
    const float* __restrict__ Wproj, const float* __restrict__ Wgate,
    const float* __restrict__ Wglin, unsigned short* __restrict__ Wpb)
{
    const int chunk = blockIdx.x;
    const int tid = threadIdx.x;
    #pragma unroll
    for (int j = 0; j < 4; ++j) {
        int u = tid * 4 + j;                 // 16B unit index 0..1023
        int p = u * 16;                      // physical byte
        int l = p ^ (((p >> 8) & 7) << 4);   // logical byte (involution)
        int r = l >> 8;                      // logical row 0..63
        int k0 = (l & 255) >> 1;             // element index (multiple of 8)
        const float* src;
        if (chunk < 8) {
            int d = chunk * 32 + (r >> 1);
            src = (r & 1) ? (Wgate + d * CC) : (Wproj + d * CC);
        } else {
            src = Wglin + ((chunk - 8) * 64 + r) * CC;
        }
        float4 v0 = *(const float4*)(src + k0);
        float4 v1 = *(const float4*)(src + k0 + 4);
        ushort4 o0, o1;
        o0.x = f2b(v0.x); o0.y = f2b(v0.y); o0.z = f2b(v0.z); o0.w = f2b(v0.w);
        o1.x = f2b(v1.x); o1.y = f2b(v1.y); o1.z = f2b(v1.z); o1.w = f2b(v1.w);
        *(ushort4*)(Wpb + chunk * 8192 + u * 8)     = o0;
        *(ushort4*)(Wpb + chunk * 8192 + u * 8 + 4) = o1;
    }
}

// ---------------------------------------------------------------------------
// Kernel 1: LN(act) -> proj/gate/glin via MFMA bf16.
// W chunks arrive preformatted via global_load_lds (no conversion VALU).
// Epilogue: shfl_xor(1) moves the gate logit to the proj lane; gated bf16
// packed stores go straight to the a/b planes (8B per even lane).
// 2 barriers per chunk.
// ---------------------------------------------------------------------------
__global__ __launch_bounds__(256) void k_ln_proj(
    const float* __restrict__ act, const float* __restrict__ mask,
    const float* __restrict__ lw, const float* __restrict__ lb,
    const unsigned short* __restrict__ Wpb,
    unsigned short* __restrict__ a_ws, unsigned short* __restrict__ b_ws,
    unsigned short* __restrict__ g_ws)
{
    __shared__ __align__(16) unsigned short Xs[128 * 136];  // 34816 B
    __shared__ __align__(16) unsigned short Wu[8192];       // 16384 B image

    const int tid = threadIdx.x;
    const int m0 = blockIdx.x * 128;

    // --- Phase 1: coalesced act load + LN + bf16 write to Xs ---
    {
        const int c4 = tid & 31;
        float4 w4 = *(const float4*)(lw + c4 * 4);
        float4 b4 = *(const float4*)(lb + c4 * 4);
        for (int it = 0; it < 16; ++it) {
            int p = (tid >> 5) + it * 8;
            float4 v = *(const float4*)(act + (size_t)(m0 + p) * CC + c4 * 4);
            float s  = v.x + v.y + v.z + v.w;
            float ss = v.x * v.x + v.y * v.y + v.z * v.z + v.w * v.w;
            #pragma unroll
            for (int ofs = 1; ofs < 32; ofs <<= 1) {
                s  += __shfl_xor(s, ofs);
                ss += __shfl_xor(ss, ofs);
            }
            float mean = s * (1.0f / 128.0f);
            float var  = ss * (1.0f / 128.0f) - mean * mean;
            float rstd = rsqrtf(var + LN_EPS);
            ushort4 o;
            o.x = f2b((v.x - mean) * rstd * w4.x + b4.x);
            o.y = f2b((v.y - mean) * rstd * w4.y + b4.y);
            o.z = f2b((v.z - mean) * rstd * w4.z + b4.z);
            o.w = f2b((v.w - mean) * rstd * w4.w + b4.w);
            *(ushort4*)&Xs[p * 136 + c4 * 4] = o;
        }
    }

    const int lane  = tid & 63;
    const int wid   = tid >> 6;
    const int row16 = lane & 15, kg = lane >> 4;
    const int wrm = (wid >> 1) * 64;
    const int wcn = (wid & 1) * 32;
    const int xrW = (row16 & 7) << 4;

    // per-lane mask fragment: m = m0 + wrm + mf*16 + kg*4 + r
    float4 mk4[4];
    #pragma unroll
    for (int mf = 0; mf < 4; ++mf)
        mk4[mf] = *(const float4*)(mask + m0 + wrm + mf * 16 + kg * 4);

    for (int chunk = 0; chunk < 10; ++chunk) {
        __syncthreads();   // Wu free / (chunk 0) Xs visible
        #pragma unroll
        for (int q = 0; q < 4; ++q) {
            int off = (wid * 4 + q) * 512 + lane * 8;   // ushort units
            __builtin_amdgcn_global_load_lds(
                (const __attribute__((address_space(1))) void*)(Wpb + chunk * 8192 + off),
                (__attribute__((address_space(3))) void*)(Wu + off), 16, 0, 0);
        }
        __syncthreads();

        // --- MFMA: 4 Mf x 2 Nf x 4 Ks ---
        f32x4 acc[4][2] = {};
        #pragma unroll
        for (int ks = 0; ks < 4; ++ks) {
            const int koff = ks * 32 + kg * 8;
            bf16x8 xa[4], wb[2];
            #pragma unroll
            for (int mf = 0; mf < 4; ++mf)
                xa[mf] = *(const bf16x8*)&Xs[(wrm + mf * 16 + row16) * 136 + koff];
            #pragma unroll
            for (int nf = 0; nf < 2; ++nf) {
                int pb = (((wcn + nf * 16 + row16) << 8) + (koff << 1)) ^ xrW;
                wb[nf] = *(const bf16x8*)((const char*)Wu + pb);
            }
            #pragma unroll
            for (int mf = 0; mf < 4; ++mf)
                #pragma unroll
                for (int nf = 0; nf < 2; ++nf)
                    acc[mf][nf] = __builtin_amdgcn_mfma_f32_16x16x32_bf16(
                        xa[mf], wb[nf], acc[mf][nf], 0, 0, 0);
        }

        // --- register-direct epilogue ---
        if (chunk < 8) {
            unsigned short* plane = (chunk < 4) ? a_ws : b_ws;
            #pragma unroll
            for (int mf = 0; mf < 4; ++mf) {
                #pragma unroll
                for (int nf = 0; nf < 2; ++nf) {
                    f32x4 p = acc[mf][nf];
                    float gx = __shfl_xor(p.x, 1);
                    float gy = __shfl_xor(p.y, 1);
                    float gz = __shfl_xor(p.z, 1);
                    float gw = __shfl_xor(p.w, 1);
                    if (!(row16 & 1)) {
                        int rn = wcn + nf * 16 + row16;
                        int D = (chunk * 32 + (rn >> 1)) & 127;
                        ushort4 o;
                        o.x = f2b(p.x * mk4[mf].x * sigmoidf(gx));
                        o.y = f2b(p.y * mk4[mf].y * sigmoidf(gy));
                        o.z = f2b(p.z * mk4[mf].z * sigmoidf(gz));
                        o.w = f2b(p.w * mk4[mf].w * sigmoidf(gw));
                        *(ushort4*)(plane + (size_t)D * NPOS +
                                    m0 + wrm + mf * 16 + kg * 4) = o;
                    }
                }
            }
        } else {
            #pragma unroll
            for (int mf = 0; mf < 4; ++mf) {
                int mb = m0 + wrm + mf * 16 + kg * 4;
                #pragma unroll
                for (int nf = 0; nf < 2; ++nf) {
                    int d = (chunk - 8) * 64 + wcn + nf * 16 + row16;
                    f32x4 p = acc[mf][nf];
                    g_ws[(size_t)(mb + 0) * CC + d] = f2b(sigmoidf(p.x));
                    g_ws[(size_t)(mb + 1) * CC + d] = f2b(sigmoidf(p.y));
                    g_ws[(size_t)(mb + 2) * CC + d] = f2b(sigmoidf(p.z));
                    g_ws[(size_t)(mb + 3) * CC + d] = f2b(sigmoidf(p.w));
                }
            }
        }
    }
}

// ---------------------------------------------------------------------------
// Kernel 2: per-channel GEMM  tT[c] = A_c * B_c^T.  (R2 body + XCD swizzle:
// 16 consecutive channels per XCD so A/B-panel reuse stays in XCD-local L2.)
// ---------------------------------------------------------------------------
__global__ __launch_bounds__(256) void k_tri(
    const unsigned short* __restrict__ a_ws,
    const unsigned short* __restrict__ b_ws,
    unsigned short* __restrict__ t_ws)
{
    __shared__ __align__(16) unsigned short As[8192];
    __shared__ __align__(16) unsigned short Bs[8192];

    const int tid  = threadIdx.x;
    const int lane = tid & 63;
    const int wid  = tid >> 6;

    const int virt = blockIdx.x;            // 0..2047
    const int xcd  = virt & 7;
    const int idx  = virt >> 3;              // 0..255
    const int c    = xcd * 16 + (idx >> 4);  // 16 channels per XCD
    const int tile = idx & 15;
    const int i0   = (tile >> 2) * 128;
    const int j0   = (tile & 3) * 128;

    const size_t plane = (size_t)c * NPOS;
    const unsigned short* Ag = a_ws + plane + (size_t)i0 * NN;
    const unsigned short* Bg = b_ws + plane + (size_t)j0 * NN;

    const int row16 = lane & 15, kg = lane >> 4;
    const int wrm = (wid >> 1) * 64;
    const int wcn = (wid & 1) * 64;
    const int xr  = (lane & 7) << 4;

    int srcOff[4];
    #pragma unroll
    for (int q = 0; q < 4; ++q) {
        int p  = (wid * 4 + q) * 1024 + lane * 16;
        int lg = p ^ (((p >> 7) & 7) << 4);
        int r = lg >> 7, k16 = (lg >> 4) & 7;
        srcOff[q] = r * NN + k16 * 8;
    }

    f32x4 acc[4][4] = {};

    for (int kt = 0; kt < 8; ++kt) {
        const int k0 = kt * 64;
        __syncthreads();
        #pragma unroll
        for (int q = 0; q < 4; ++q) {
            int ldsOff = (wid * 4 + q) * 512;
            __builtin_amdgcn_global_load_lds(
                (const __attribute__((address_space(1))) void*)(Ag + srcOff[q] + k0),
                (__attribute__((address_space(3))) void*)(As + ldsOff), 16, 0, 0);
            __builtin_amdgcn_global_load_lds(
                (const __attribute__((address_space(1))) void*)(Bg + srcOff[q] + k0),
                (__attribute__((address_space(3))) void*)(Bs + ldsOff), 16, 0, 0);
        }
        __syncthreads();

        #pragma unroll
        for (int ks = 0; ks < 2; ++ks) {
            const int kb = ks * 64 + kg * 16;
            bf16x8 af[4], bfr[4];
            #pragma unroll
            for (int mf = 0; mf < 4; ++mf) {
                int lA = ((wrm + mf * 16 + row16) << 7) + kb;
                af[mf] = *(const bf16x8*)((const char*)As + (lA ^ xr));
            }
            #pragma unroll
            for (int nf = 0; nf < 4; ++nf) {
                int lB = ((wcn + nf * 16 + row16) << 7) + kb;
                bfr[nf] = *(const bf16x8*)((const char*)Bs + (lB ^ xr));
            }
            #pragma unroll
            for (int mf = 0; mf < 4; ++mf)
                #pragma unroll
                for (int nf = 0; nf < 4; ++nf)
                    acc[mf][nf] = __builtin_amdgcn_mfma_f32_16x16x32_bf16(
                        af[mf], bfr[nf], acc[mf][nf], 0, 0, 0);
        }
    }

    unsigned short* tp = t_ws + plane;
    #pragma unroll
    for (int mf = 0; mf < 4; ++mf) {
        int i = i0 + wrm + mf * 16 + kg * 4;
        #pragma unroll
        for (int nf = 0; nf < 4; ++nf) {
            int j = j0 + wcn + nf * 16 + row16;
            f32x4 v = acc[mf][nf];
            tp[(size_t)(i + 0) * NN + j] = f2b(v.x);
            tp[(size_t)(i + 1) * NN + j] = f2b(v.y);
            tp[(size_t)(i + 2) * NN + j] = f2b(v.z);
            tp[(size_t)(i + 3) * NN + j] = f2b(v.w);
        }
    }
}

// ---------------------------------------------------------------------------
// Kernel 3: out = (LN_c(t) @ W_out^T) * g.  (unchanged from R4, verified)
// ---------------------------------------------------------------------------
__global__ __launch_bounds__(256) void k_out(
    const unsigned short* __restrict__ tT,
    const unsigned short* __restrict__ g_ws,
    const float* __restrict__ lw, const float* __restrict__ lb,
    const float* __restrict__ Wout,
    float* __restrict__ out)
{
    __shared__ __align__(16) float Xf[128 * 68];
    __shared__ __align__(16) unsigned short Wt[128 * 132];

    const int tid = threadIdx.x;
    const int m0 = blockIdx.x * 64;

    #pragma unroll
    for (int it = 0; it < 4; ++it) {
        int c  = (tid >> 3) + it * 32;
        int mg = tid & 7;
        uint4 u = *(const uint4*)(tT + (size_t)c * NPOS + m0 + mg * 8);
        float f[8];
        unpack8(u, f);
        float* dst = &Xf[c * 68 + mg * 8];
        #pragma unroll
        for (int t = 0; t < 8; ++t) dst[t] = f[t];
    }
    #pragma unroll
    for (int it = 0; it < 16; ++it) {
        int idx = tid + it * 256;
        int d = idx >> 5, c4 = idx & 31;
        float4 v = *(const float4*)(Wout + d * CC + c4 * 4);
        Wt[(c4 * 4 + 0) * 132 + d] = f2b(v.x);
        Wt[(c4 * 4 + 1) * 132 + d] = f2b(v.y);
        Wt[(c4 * 4 + 2) * 132 + d] = f2b(v.z);
        Wt[(c4 * 4 + 3) * 132 + d] = f2b(v.w);
    }
    __syncthreads();

    {
        int m = tid >> 2, q = tid & 3;
        float s = 0.f, ss = 0.f;
        #pragma unroll
        for (int t = 0; t < 32; ++t) {
            float v = Xf[(q * 32 + t) * 68 + m];
            s += v; ss += v * v;
        }
        s += __shfl_xor(s, 1); ss += __shfl_xor(ss, 1);
        s += __shfl_xor(s, 2); ss += __shfl_xor(ss, 2);
        float mean = s * (1.0f / 128.0f);
        float var  = ss * (1.0f / 128.0f) - mean * mean;
        float rstd = rsqrtf(var + LN_EPS);
        #pragma unroll
        for (int t = 0; t < 32; ++t) {
            int c = q * 32 + t;
            float v = Xf[c * 68 + m];
            Xf[c * 68 + m] = (v - mean) * rstd * lw[c] + lb[c];
        }
    }
    __syncthreads();

    const int tx = tid & 15, ty = tid >> 4;
    float acc[4][8] = {};
    #pragma unroll 4
    for (int c = 0; c < 128; ++c) {
        float4 xv = *(const float4*)&Xf[c * 68 + ty * 4];
        const unsigned short* wp = &Wt[c * 132 + tx * 8];
        uint2 wa = *(const uint2*)(wp);
        uint2 wbu = *(const uint2*)(wp + 4);
        float w[8];
        w[0] = bitf(wa.x << 16);  w[1] = bitf(wa.x & 0xFFFF0000u);
        w[2] = bitf(wa.y << 16);  w[3] = bitf(wa.y & 0xFFFF0000u);
        w[4] = bitf(wbu.x << 16); w[5] = bitf(wbu.x & 0xFFFF0000u);
        w[6] = bitf(wbu.y << 16); w[7] = bitf(wbu.y & 0xFFFF0000u);
        float xr[4] = {xv.x, xv.y, xv.z, xv.w};
        #pragma unroll
        for (int i2 = 0; i2 < 4; ++i2)
            #pragma unroll
            for (int j = 0; j < 8; ++j)
                acc[i2][j] += xr[i2] * w[j];
    }

    #pragma unroll
    for (int i2 = 0; i2 < 4; ++i2) {
        int m = m0 + ty * 4 + i2;
        const unsigned short* gp = g_ws + (size_t)m * CC + tx * 8;
        ushort4 ga = *(const ushort4*)(gp);
        ushort4 gb = *(const ushort4*)(gp + 4);
        float4 o0, o1;
        o0.x = acc[i2][0] * b2f(ga.x);
        o0.y = acc[i2][1] * b2f(ga.y);
        o0.z = acc[i2][2] * b2f(ga.z);
        o0.w = acc[i2][3] * b2f(ga.w);
        o1.x = acc[i2][4] * b2f(gb.x);
        o1.y = acc[i2][5] * b2f(gb.y);
        o1.z = acc[i2][6] * b2f(gb.z);
        o1.w = acc[i2][7] * b2f(gb.w);
        *(float4*)(out + (size_t)m * CC + tx * 8) = o0;
        *(float4*)(out + (size_t)m * CC + tx * 8 + 4) = o1;
    }
}

// ---------------------------------------------------------------------------
extern "C" void kernel_launch(void* const* d_in, const int* in_sizes, int n_in,
                              void* d_out, int out_size, void* d_ws, size_t ws_size,
                              hipStream_t stream) {
    const float* act   = (const float*)d_in[0];
    const float* mask  = (const float*)d_in[1];
    const float* lnw   = (const float*)d_in[2];
    const float* lnb   = (const float*)d_in[3];
    const float* Wproj = (const float*)d_in[4];
    const float* Wgate = (const float*)d_in[5];
    const float* lncw  = (const float*)d_in[6];
    const float* lncb  = (const float*)d_in[7];
    const float* Wout  = (const float*)d_in[8];
    const float* Wglin = (const float*)d_in[9];
    float* out = (float*)d_out;

    char* ws = (char*)d_ws;
    unsigned short* a_ws = (unsigned short*)(ws);
    unsigned short* b_ws = (unsigned short*)(ws + 67108864);
    unsigned short* g_ws = (unsigned short*)(ws + 134217728);
    unsigned short* t_ws = (unsigned short*)(ws + 201326592);
    unsigned short* Wpb  = t_ws;   // overlays tT head; dead before k_tri writes

    k_wprep<<<dim3(10), dim3(256), 0, stream>>>(Wproj, Wgate, Wglin, Wpb);

    k_ln_proj<<<dim3(2048), dim3(256), 0, stream>>>(
        act, mask, lnw, lnb, Wpb, a_ws, b_ws, g_ws);

    k_tri<<<dim3(2048), dim3(256), 0, stream>>>(a_ws, b_ws, t_ws);

    k_out<<<dim3(4096), dim3(256), 0, stream>>>(
        t_ws, g_ws, lncw, lncb, Wout, out);
}

// Round 7
// 531.807 us; speedup vs baseline: 1.2258x; 1.0646x over previous
//
#include <hip/hip_runtime.h>

// TriangleMultiplicationCpp (OUTGOING), N=512, C=128, fp32 in/out.
// Round 8 = Round 7 resubmitted verbatim (infra failure, no verdict).
// k1 shuffle-free epilogue (R6) + k_out reverted to the R4/R5-VERIFIED
// fp32-X VALU GEMM (MFMA k_out retired: 2 unexplained fails).
// Workspace layout (bytes), all 67,108,864 each:
//   aT[c][m] @ 0      bT[c][m] @ 64M      g[m][d] @ 128M      tT[c][m] @ 192M
// Wpb (160 KB bf16 weight image) overlays the head of the tT region.

#define NN 512
#define CC 128
#define NPOS (NN * NN)
#define LN_EPS 1e-5f

typedef __attribute__((ext_vector_type(8))) short bf16x8;
typedef __attribute__((ext_vector_type(4))) float f32x4;

__device__ __forceinline__ float bitf(unsigned int u) {
    return __builtin_bit_cast(float, u);
}
__device__ __forceinline__ float b2f(unsigned short u) {
    return bitf(((unsigned int)u) << 16);
}
__device__ __forceinline__ unsigned short f2b(float f) {
    unsigned int u = __builtin_bit_cast(unsigned int, f);
    u = u + 0x7FFFu + ((u >> 16) & 1u);   // RTNE
    return (unsigned short)(u >> 16);
}
__device__ __forceinline__ float sigmoidf(float x) {
    return 1.0f / (1.0f + __expf(-x));
}
__device__ __forceinline__ void unpack8(uint4 u, float* dst) {
    dst[0] = bitf(u.x << 16); dst[1] = bitf(u.x & 0xFFFF0000u);
    dst[2] = bitf(u.y << 16); dst[3] = bitf(u.y & 0xFFFF0000u);
    dst[4] = bitf(u.z << 16); dst[5] = bitf(u.z & 0xFFFF0000u);
    dst[6] = bitf(u.w << 16); dst[7] = bitf(u.w & 0xFFFF0000u);
}

// ---------------------------------------------------------------------------
// Kernel 0: weight prep (R6 layout). Physical LDS image per 64x128 bf16 chunk
// with read-side XOR swizzle baked in (byte p holds logical p^(((p>>8)&7)<<4)).
// chunk<8 rows: half = r>>5, row16 = r&15, gate = r&16;
//   d = chunk*32 + half*16 + row16.
// ---------------------------------------------------------------------------
__global__ __launch_bounds__(256) void k_wprep(
    const float* __restrict__ Wproj, const float* __restrict__ Wgate,
    const float* __restrict__ Wglin, unsigned short* __restrict__ Wpb)
{
    const int chunk = blockIdx.x;
    const int tid = threadIdx.x;
    #pragma unroll
    for (int j = 0; j < 4; ++j) {
        int u = tid * 4 + j;                 // 16B unit index 0..1023
        int p = u * 16;                      // physical byte
        int l = p ^ (((p >> 8) & 7) << 4);   // logical byte (involution)
        int r = l >> 8;                      // logical row 0..63
        int k0 = (l & 255) >> 1;             // element index (multiple of 8)
        const float* src;
        if (chunk < 8) {
            int d = chunk * 32 + ((r >> 5) * 16) + (r & 15);
            src = (r & 16) ? (Wgate + d * CC) : (Wproj + d * CC);
        } else {
            src = Wglin + ((chunk - 8) * 64 + r) * CC;
        }
        float4 v0 = *(const float4*)(src + k0);
        float4 v1 = *(const float4*)(src + k0 + 4);
        ushort4 o0, o1;
        o0.x = f2b(v0.x); o0.y = f2b(v0.y); o0.z = f2b(v0.z); o0.w = f2b(v0.w);
        o1.x = f2b(v1.x); o1.y = f2b(v1.y); o1.z = f2b(v1.z); o1.w = f2b(v1.w);
        *(ushort4*)(Wpb + chunk * 8192 + u * 8)     = o0;
        *(ushort4*)(Wpb + chunk * 8192 + u * 8 + 4) = o1;
    }
}

// ---------------------------------------------------------------------------
// Kernel 1: LN(act) -> proj/gate/glin via MFMA bf16. Shuffle-free epilogue:
// lane holds proj (nf=0) and its own gate (nf=1) for the same d.
// ---------------------------------------------------------------------------
__global__ __launch_bounds__(256) void k_ln_proj(
    const float* __restrict__ act, const float* __restrict__ mask,
    const float* __restrict__ lw, const float* __restrict__ lb,
    const unsigned short* __restrict__ Wpb,
    unsigned short* __restrict__ a_ws, unsigned short* __restrict__ b_ws,
    unsigned short* __restrict__ g_ws)
{
    __shared__ __align__(16) unsigned short Xs[128 * 136];  // 34816 B
    __shared__ __align__(16) unsigned short Wu[8192];       // 16384 B image

    const int tid = threadIdx.x;
    const int m0 = blockIdx.x * 128;

    // --- Phase 1: coalesced act load + LN + bf16 write to Xs ---
    {
        const int c4 = tid & 31;
        float4 w4 = *(const float4*)(lw + c4 * 4);
        float4 b4 = *(const float4*)(lb + c4 * 4);
        for (int it = 0; it < 16; ++it) {
            int p = (tid >> 5) + it * 8;
            float4 v = *(const float4*)(act + (size_t)(m0 + p) * CC + c4 * 4);
            float s  = v.x + v.y + v.z + v.w;
            float ss = v.x * v.x + v.y * v.y + v.z * v.z + v.w * v.w;
            #pragma unroll
            for (int ofs = 1; ofs < 32; ofs <<= 1) {
                s  += __shfl_xor(s, ofs);
                ss += __shfl_xor(ss, ofs);
            }
            float mean = s * (1.0f / 128.0f);
            float var  = ss * (1.0f / 128.0f) - mean * mean;
            float rstd = rsqrtf(var + LN_EPS);
            ushort4 o;
            o.x = f2b((v.x - mean) * rstd * w4.x + b4.x);
            o.y = f2b((v.y - mean) * rstd * w4.y + b4.y);
            o.z = f2b((v.z - mean) * rstd * w4.z + b4.z);
            o.w = f2b((v.w - mean) * rstd * w4.w + b4.w);
            *(ushort4*)&Xs[p * 136 + c4 * 4] = o;
        }
    }

    const int lane  = tid & 63;
    const int wid   = tid >> 6;
    const int row16 = lane & 15, kg = lane >> 4;
    const int wrm = (wid >> 1) * 64;
    const int wcn = (wid & 1) * 32;
    const int xrW = (row16 & 7) << 4;

    float4 mk4[4];
    #pragma unroll
    for (int mf = 0; mf < 4; ++mf)
        mk4[mf] = *(const float4*)(mask + m0 + wrm + mf * 16 + kg * 4);

    for (int chunk = 0; chunk < 10; ++chunk) {
        __syncthreads();
        #pragma unroll
        for (int q = 0; q < 4; ++q) {
            int off = (wid * 4 + q) * 512 + lane * 8;
            __builtin_amdgcn_global_load_lds(
                (const __attribute__((address_space(1))) void*)(Wpb + chunk * 8192 + off),
                (__attribute__((address_space(3))) void*)(Wu + off), 16, 0, 0);
        }
        __syncthreads();

        // --- MFMA: 4 Mf x 2 Nf x 4 Ks ---
        f32x4 acc[4][2] = {};
        #pragma unroll
        for (int ks = 0; ks < 4; ++ks) {
            const int koff = ks * 32 + kg * 8;
            bf16x8 xa[4], wb[2];
            #pragma unroll
            for (int mf = 0; mf < 4; ++mf)
                xa[mf] = *(const bf16x8*)&Xs[(wrm + mf * 16 + row16) * 136 + koff];
            #pragma unroll
            for (int nf = 0; nf < 2; ++nf) {
                int pb = (((wcn + nf * 16 + row16) << 8) + (koff << 1)) ^ xrW;
                wb[nf] = *(const bf16x8*)((const char*)Wu + pb);
            }
            #pragma unroll
            for (int mf = 0; mf < 4; ++mf)
                #pragma unroll
                for (int nf = 0; nf < 2; ++nf)
                    acc[mf][nf] = __builtin_amdgcn_mfma_f32_16x16x32_bf16(
                        xa[mf], wb[nf], acc[mf][nf], 0, 0, 0);
        }

        // --- shuffle-free epilogue ---
        if (chunk < 8) {
            unsigned short* plane = (chunk < 4) ? a_ws : b_ws;
            int D = (chunk & 3) * 32 + (wid & 1) * 16 + row16;
            unsigned short* pb = plane + (size_t)D * NPOS + m0 + wrm + kg * 4;
            #pragma unroll
            for (int mf = 0; mf < 4; ++mf) {
                f32x4 p = acc[mf][0];
                f32x4 g = acc[mf][1];
                ushort4 o;
                o.x = f2b(p.x * mk4[mf].x * sigmoidf(g.x));
                o.y = f2b(p.y * mk4[mf].y * sigmoidf(g.y));
                o.z = f2b(p.z * mk4[mf].z * sigmoidf(g.z));
                o.w = f2b(p.w * mk4[mf].w * sigmoidf(g.w));
                *(ushort4*)(pb + mf * 16) = o;
            }
        } else {
            #pragma unroll
            for (int mf = 0; mf < 4; ++mf) {
                int mb = m0 + wrm + mf * 16 + kg * 4;
                #pragma unroll
                for (int nf = 0; nf < 2; ++nf) {
                    int d = (chunk - 8) * 64 + wcn + nf * 16 + row16;
                    f32x4 p = acc[mf][nf];
                    g_ws[(size_t)(mb + 0) * CC + d] = f2b(sigmoidf(p.x));
                    g_ws[(size_t)(mb + 1) * CC + d] = f2b(sigmoidf(p.y));
                    g_ws[(size_t)(mb + 2) * CC + d] = f2b(sigmoidf(p.z));
                    g_ws[(size_t)(mb + 3) * CC + d] = f2b(sigmoidf(p.w));
                }
            }
        }
    }
}

// ---------------------------------------------------------------------------
// Kernel 2: per-channel GEMM  tT[c] = A_c * B_c^T.  (unchanged, XCD swizzle)
// ---------------------------------------------------------------------------
__global__ __launch_bounds__(256) void k_tri(
    const unsigned short* __restrict__ a_ws,
    const unsigned short* __restrict__ b_ws,
    unsigned short* __restrict__ t_ws)
{
    __shared__ __align__(16) unsigned short As[8192];
    __shared__ __align__(16) unsigned short Bs[8192];

    const int tid  = threadIdx.x;
    const int lane = tid & 63;
    const int wid  = tid >> 6;

    const int virt = blockIdx.x;
    const int xcd  = virt & 7;
    const int idx  = virt >> 3;
    const int c    = xcd * 16 + (idx >> 4);
    const int tile = idx & 15;
    const int i0   = (tile >> 2) * 128;
    const int j0   = (tile & 3) * 128;

    const size_t plane = (size_t)c * NPOS;
    const unsigned short* Ag = a_ws + plane + (size_t)i0 * NN;
    const unsigned short* Bg = b_ws + plane + (size_t)j0 * NN;

    const int row16 = lane & 15, kg = lane >> 4;
    const int wrm = (wid >> 1) * 64;
    const int wcn = (wid & 1) * 64;
    const int xr  = (lane & 7) << 4;

    int srcOff[4];
    #pragma unroll
    for (int q = 0; q < 4; ++q) {
        int p  = (wid * 4 + q) * 1024 + lane * 16;
        int lg = p ^ (((p >> 7) & 7) << 4);
        int r = lg >> 7, k16 = (lg >> 4) & 7;
        srcOff[q] = r * NN + k16 * 8;
    }

    f32x4 acc[4][4] = {};

    for (int kt = 0; kt < 8; ++kt) {
        const int k0 = kt * 64;
        __syncthreads();
        #pragma unroll
        for (int q = 0; q < 4; ++q) {
            int ldsOff = (wid * 4 + q) * 512;
            __builtin_amdgcn_global_load_lds(
                (const __attribute__((address_space(1))) void*)(Ag + srcOff[q] + k0),
                (__attribute__((address_space(3))) void*)(As + ldsOff), 16, 0, 0);
            __builtin_amdgcn_global_load_lds(
                (const __attribute__((address_space(1))) void*)(Bg + srcOff[q] + k0),
                (__attribute__((address_space(3))) void*)(Bs + ldsOff), 16, 0, 0);
        }
        __syncthreads();

        #pragma unroll
        for (int ks = 0; ks < 2; ++ks) {
            const int kb = ks * 64 + kg * 16;
            bf16x8 af[4], bfr[4];
            #pragma unroll
            for (int mf = 0; mf < 4; ++mf) {
                int lA = ((wrm + mf * 16 + row16) << 7) + kb;
                af[mf] = *(const bf16x8*)((const char*)As + (lA ^ xr));
            }
            #pragma unroll
            for (int nf = 0; nf < 4; ++nf) {
                int lB = ((wcn + nf * 16 + row16) << 7) + kb;
                bfr[nf] = *(const bf16x8*)((const char*)Bs + (lB ^ xr));
            }
            #pragma unroll
            for (int mf = 0; mf < 4; ++mf)
                #pragma unroll
                for (int nf = 0; nf < 4; ++nf)
                    acc[mf][nf] = __builtin_amdgcn_mfma_f32_16x16x32_bf16(
                        af[mf], bfr[nf], acc[mf][nf], 0, 0, 0);
        }
    }

    unsigned short* tp = t_ws + plane;
    #pragma unroll
    for (int mf = 0; mf < 4; ++mf) {
        int i = i0 + wrm + mf * 16 + kg * 4;
        #pragma unroll
        for (int nf = 0; nf < 4; ++nf) {
            int j = j0 + wcn + nf * 16 + row16;
            f32x4 v = acc[mf][nf];
            tp[(size_t)(i + 0) * NN + j] = f2b(v.x);
            tp[(size_t)(i + 1) * NN + j] = f2b(v.y);
            tp[(size_t)(i + 2) * NN + j] = f2b(v.z);
            tp[(size_t)(i + 3) * NN + j] = f2b(v.w);
        }
    }
}

// ---------------------------------------------------------------------------
// Kernel 3: out = (LN_c(t) @ W_out^T) * g.  R4/R5-VERIFIED fp32-X VALU GEMM.
//   Xf[c][m] fp32, stride 68 (c-major from tT; GEMM reads wave-broadcast)
//   Wt[c][d] bf16, stride 132 (transposed W: lane-varying d -> 2-way max)
// Block: 64 positions, full d=128. Thread: 4 m x 8 d outer product.
// ---------------------------------------------------------------------------
__global__ __launch_bounds__(256) void k_out(
    const unsigned short* __restrict__ tT,
    const unsigned short* __restrict__ g_ws,
    const float* __restrict__ lw, const float* __restrict__ lb,
    const float* __restrict__ Wout,
    float* __restrict__ out)
{
    __shared__ __align__(16) float Xf[128 * 68];            // 34816 B
    __shared__ __align__(16) unsigned short Wt[128 * 132];  // 33792 B

    const int tid = threadIdx.x;
    const int m0 = blockIdx.x * 64;

    #pragma unroll
    for (int it = 0; it < 4; ++it) {
        int c  = (tid >> 3) + it * 32;
        int mg = tid & 7;
        uint4 u = *(const uint4*)(tT + (size_t)c * NPOS + m0 + mg * 8);
        float f[8];
        unpack8(u, f);
        float* dst = &Xf[c * 68 + mg * 8];
        #pragma unroll
        for (int t = 0; t < 8; ++t) dst[t] = f[t];
    }
    #pragma unroll
    for (int it = 0; it < 16; ++it) {
        int idx = tid + it * 256;
        int d = idx >> 5, c4 = idx & 31;
        float4 v = *(const float4*)(Wout + d * CC + c4 * 4);
        Wt[(c4 * 4 + 0) * 132 + d] = f2b(v.x);
        Wt[(c4 * 4 + 1) * 132 + d] = f2b(v.y);
        Wt[(c4 * 4 + 2) * 132 + d] = f2b(v.z);
        Wt[(c4 * 4 + 3) * 132 + d] = f2b(v.w);
    }
    __syncthreads();

    {
        int m = tid >> 2, q = tid & 3;
        float s = 0.f, ss = 0.f;
        #pragma unroll
        for (int t = 0; t < 32; ++t) {
            float v = Xf[(q * 32 + t) * 68 + m];
            s += v; ss += v * v;
        }
        s += __shfl_xor(s, 1); ss += __shfl_xor(ss, 1);
        s += __shfl_xor(s, 2); ss += __shfl_xor(ss, 2);
        float mean = s * (1.0f / 128.0f);
        float var  = ss * (1.0f / 128.0f) - mean * mean;
        float rstd = rsqrtf(var + LN_EPS);
        #pragma unroll
        for (int t = 0; t < 32; ++t) {
            int c = q * 32 + t;
            float v = Xf[c * 68 + m];
            Xf[c * 68 + m] = (v - mean) * rstd * lw[c] + lb[c];
        }
    }
    __syncthreads();

    const int tx = tid & 15, ty = tid >> 4;
    float acc[4][8] = {};
    #pragma unroll 4
    for (int c = 0; c < 128; ++c) {
        float4 xv = *(const float4*)&Xf[c * 68 + ty * 4];
        const unsigned short* wp = &Wt[c * 132 + tx * 8];
        uint2 wa = *(const uint2*)(wp);
        uint2 wbu = *(const uint2*)(wp + 4);
        float w[8];
        w[0] = bitf(wa.x << 16);  w[1] = bitf(wa.x & 0xFFFF0000u);
        w[2] = bitf(wa.y << 16);  w[3] = bitf(wa.y & 0xFFFF0000u);
        w[4] = bitf(wbu.x << 16); w[5] = bitf(wbu.x & 0xFFFF0000u);
        w[6] = bitf(wbu.y << 16); w[7] = bitf(wbu.y & 0xFFFF0000u);
        float xr[4] = {xv.x, xv.y, xv.z, xv.w};
        #pragma unroll
        for (int i2 = 0; i2 < 4; ++i2)
            #pragma unroll
            for (int j = 0; j < 8; ++j)
                acc[i2][j] += xr[i2] * w[j];
    }

    #pragma unroll
    for (int i2 = 0; i2 < 4; ++i2) {
        int m = m0 + ty * 4 + i2;
        const unsigned short* gp = g_ws + (size_t)m * CC + tx * 8;
        ushort4 ga = *(const ushort4*)(gp);
        ushort4 gb = *(const ushort4*)(gp + 4);
        float4 o0, o1;
        o0.x = acc[i2][0] * b2f(ga.x);
        o0.y = acc[i2][1] * b2f(ga.y);
        o0.z = acc[i2][2] * b2f(ga.z);
        o0.w = acc[i2][3] * b2f(ga.w);
        o1.x = acc[i2][4] * b2f(gb.x);
        o1.y = acc[i2][5] * b2f(gb.y);
        o1.z = acc[i2][6] * b2f(gb.z);
        o1.w = acc[i2][7] * b2f(gb.w);
        *(float4*)(out + (size_t)m * CC + tx * 8) = o0;
        *(float4*)(out + (size_t)m * CC + tx * 8 + 4) = o1;
    }
}

// ---------------------------------------------------------------------------
extern "C" void kernel_launch(void* const* d_in, const int* in_sizes, int n_in,
                              void* d_out, int out_size, void* d_ws, size_t ws_size,
                              hipStream_t stream) {
    const float* act   = (const float*)d_in[0];
    const float* mask  = (const float*)d_in[1];
    const float* lnw   = (const float*)d_in[2];
    const float* lnb   = (const float*)d_in[3];
    const float* Wproj = (const float*)d_in[4];
    const float* Wgate = (const float*)d_in[5];
    const float* lncw  = (const float*)d_in[6];
    const float* lncb  = (const float*)d_in[7];
    const float* Wout  = (const float*)d_in[8];
    const float* Wglin = (const float*)d_in[9];
    float* out = (float*)d_out;

    char* ws = (char*)d_ws;
    unsigned short* a_ws = (unsigned short*)(ws);
    unsigned short* b_ws = (unsigned short*)(ws + 67108864);
    unsigned short* g_ws = (unsigned short*)(ws + 134217728);
    unsigned short* t_ws = (unsigned short*)(ws + 201326592);
    unsigned short* Wpb  = t_ws;   // overlays tT head; dead before k_tri writes

    k_wprep<<<dim3(10), dim3(256), 0, stream>>>(Wproj, Wgate, Wglin, Wpb);

    k_ln_proj<<<dim3(2048), dim3(256), 0, stream>>>(
        act, mask, lnw, lnb, Wpb, a_ws, b_ws, g_ws);

    k_tri<<<dim3(2048), dim3(256), 0, stream>>>(a_ws, b_ws, t_ws);

    k_out<<<dim3(4096), dim3(256), 0, stream>>>(
        t_ws, g_ws, lncw, lncb, Wout, out);
}